// Round 16
// baseline (526.809 us; speedup 1.0000x reference)
//
#include <hip/hip_runtime.h>

typedef __bf16 bf16_t;
typedef __bf16 bf16x8 __attribute__((ext_vector_type(8)));
typedef __bf16 bf16x4 __attribute__((ext_vector_type(4)));
typedef float  f32x4  __attribute__((ext_vector_type(4)));
typedef unsigned u32x4 __attribute__((ext_vector_type(4)));

#define SEQ    1024
#define DMODEL 4096
#define NHQ    32
#define NHKV   8
#define HDIM   128

// async global->LDS, 16B per lane; LDS dest must be linear (base + lane*16)
#define GLOAD_LDS16(g, l)                                                  \
    __builtin_amdgcn_global_load_lds(                                      \
        (const __attribute__((address_space(1))) unsigned int*)(g),        \
        (__attribute__((address_space(3))) unsigned int*)(l), 16, 0, 0)

// ---------------------------------------------------------------------------
// fp32 -> bf16 convert, 8 elems/thread
// ---------------------------------------------------------------------------
__global__ __launch_bounds__(256)
void f2b(const float* __restrict__ in, bf16_t* __restrict__ out, int n8)
{
    int i = blockIdx.x * 256 + threadIdx.x;
    if (i >= n8) return;
    const float4* p = (const float4*)in + 2 * (size_t)i;
    float4 a = p[0], b = p[1];
    bf16x8 o;
    o[0] = (bf16_t)a.x; o[1] = (bf16_t)a.y; o[2] = (bf16_t)a.z; o[3] = (bf16_t)a.w;
    o[4] = (bf16_t)b.x; o[5] = (bf16_t)b.y; o[6] = (bf16_t)b.z; o[7] = (bf16_t)b.w;
    *((bf16x8*)out + i) = o;
}

#define MFMA_(a, b, c) __builtin_amdgcn_mfma_f32_16x16x32_bf16(a, b, c, 0, 0, 0)
#define BAR    __builtin_amdgcn_s_barrier()
#define SCB    __builtin_amdgcn_sched_barrier(0)
#define PRIO1  __builtin_amdgcn_s_setprio(1)
#define PRIO0  __builtin_amdgcn_s_setprio(0)
#define WVM4   do { asm volatile("s_waitcnt vmcnt(4)" ::: "memory"); SCB; } while (0)

// ---------------------------------------------------------------------------
// NEW (round-16, A/B test on Q-proj only): 256x128-tile GEMM, 8 waves as
// 4Mx2N (per-wave 64x64, acc[4][4]=64 VGPR -> ~110 total <= 128), BK=32,
// double-buffered 48KB LDS, __launch_bounds__(512,4) -> 2 BLOCKS/CU.
// Mechanism: every intra-block schedule variant pinned at 119us/50% MfmaUtil
// because 1 block/CU leaves the matrix pipes idle during the block's
// barrier/LDS phases. 2 co-resident blocks overlap cross-block (m97/m114
// mechanism). Sync = proven-safe r11-attn skeleton: prefetch(t+1, buf^1) ->
// compute(buf) -> __syncthreads (full drain; publishes prefetch; WAR-safe:
// stage target buf^1 was last read one barrier earlier).
// Swizzle: 16B chunk ^= (row>>1)&3 within 64B rows (2-way, free), staged
// via pre-swizzled global source + linear LDS dest (rule #21).
// ---------------------------------------------------------------------------
#define STG2(b_, ktb) do {                                                 \
    GLOAD_LDS16(aS + (ktb),             ldsA[b_] + t * 16);                \
    GLOAD_LDS16(aS + 128 * Krb + (ktb), ldsA[b_] + 8192 + t * 16);         \
    GLOAD_LDS16(bS + (ktb),             ldsB[b_] + t * 16);                \
} while (0)

template<bool OUT_F32>
__global__ __launch_bounds__(512, 4)
void gemm_mn(const bf16_t* __restrict__ A, const bf16_t* __restrict__ B,
             void* __restrict__ Cv, int M, int N, int K, int nbn)
{
    __shared__ __align__(16) char ldsA[2][16384];   // 256 rows x 64B per buf
    __shared__ __align__(16) char ldsB[2][8192];    // 128 rows x 64B per buf

    const int nwg = gridDim.x;
    const int bid0 = blockIdx.x;
    const int bid = (bid0 & 7) * (nwg >> 3) + (bid0 >> 3);   // XCD swizzle
    const int bm = bid / nbn, bn = bid % nbn;
    const int t = threadIdx.x;
    const int lane = t & 63, wid = t >> 6;
    const int wm = wid >> 1, wn = wid & 1;          // 4M x 2N waves
    const int l15 = lane & 15, lg = lane >> 4;
    const int m0 = bm * 256, n0 = bn * 128;

    const int Krb = K * 2;
    const int srow = t >> 2;                                  // 0..127
    const int scol0 = (((t & 3) ^ ((srow >> 1) & 3)) << 4);   // pre-swizzled src
    const char* aS = (const char*)A + (size_t)(m0 + srow) * Krb + scol0;
    const char* bS = (const char*)B + (size_t)(n0 + srow) * Krb + scol0;

    const int rchunk = ((lg ^ ((l15 >> 1) & 3)) << 4);
    const int aRow = (wm * 64 + l15) * 64 + rchunk;
    const int bRow = (wn * 64 + l15) * 64 + rchunk;

    const int NT = K >> 5;                                    // K-tiles of 32
    f32x4 acc[4][4] = {};

    STG2(0, 0);
    __syncthreads();                                          // tile 0 landed

    for (int tt = 0; tt < NT; ++tt) {
        const int buf = tt & 1;
        const int ks = (tt + 1 < NT) ? (tt + 1) * 64 : 0;     // K-byte offset
        STG2(buf ^ 1, ks);                                    // prefetch t+1

        bf16x8 af[4], bf[4];
        #pragma unroll
        for (int m = 0; m < 4; ++m)
            af[m] = *(const bf16x8*)(ldsA[buf] + aRow + m * 1024);
        #pragma unroll
        for (int n = 0; n < 4; ++n)
            bf[n] = *(const bf16x8*)(ldsB[buf] + bRow + n * 1024);
        PRIO1;
        #pragma unroll
        for (int m = 0; m < 4; ++m)
            #pragma unroll
            for (int n = 0; n < 4; ++n)
                acc[m][n] = MFMA_(af[m], bf[n], acc[m][n]);
        PRIO0;

        __syncthreads();   // drains prefetch (landed under compute) + swap
    }

    // epilogue: D col = lane&15, row = (lane>>4)*4 + i
    #pragma unroll
    for (int m = 0; m < 4; ++m) {
        int row0 = m0 + wm * 64 + m * 16 + lg * 4;
        #pragma unroll
        for (int n = 0; n < 4; ++n) {
            int col = n0 + wn * 64 + n * 16 + l15;
            #pragma unroll
            for (int i = 0; i < 4; ++i) {
                if constexpr (OUT_F32)
                    ((float*)Cv)[(size_t)(row0 + i) * N + col] = acc[m][n][i];
                else
                    ((bf16_t*)Cv)[(size_t)(row0 + i) * N + col] = (bf16_t)acc[m][n][i];
            }
        }
    }
}

// ---------------------------------------------------------------------------
// 256x256 8-wave GEMM -- ROUND-11 VERSION (119 us, MfmaUtil 50%), kept for
// the O-projection as the A/B control this round.
// ---------------------------------------------------------------------------
#define SA(bufo, half, ktb)  do {                                          \
    const char* g_ = ((half) ? aS1 : aS0) + (ktb);                         \
    GLOAD_LDS16(g_,      sd + (bufo) + (half) * 8192);                     \
    GLOAD_LDS16(g_ + 64, sd + (bufo) + (half) * 8192 + 16384);             \
} while (0)
#define SB(bufo, half, ktb)  do {                                          \
    const char* g_ = ((half) ? bS1 : bS0) + (ktb);                         \
    GLOAD_LDS16(g_,      sd + (bufo) + 32768 + (half) * 8192);             \
    GLOAD_LDS16(g_ + 64, sd + (bufo) + 32768 + (half) * 8192 + 16384);     \
} while (0)
#define LDA(bufo, mh) do { _Pragma("unroll")                               \
    for (int j = 0; j < 4; ++j) {                                          \
        afq[j][0] = *(const bf16x8*)(lds + (bufo) + aRow + (mh)*4096 + j*1024);         \
        afq[j][1] = *(const bf16x8*)(lds + (bufo) + aRow + (mh)*4096 + j*1024 + 16384); \
    } } while (0)
#define LDB(bufo, nh, dst) do { _Pragma("unroll")                          \
    for (int n2 = 0; n2 < 2; ++n2) {                                       \
        dst[n2][0] = *(const bf16x8*)(lds + (bufo) + bRow + (nh)*2048 + n2*1024);         \
        dst[n2][1] = *(const bf16x8*)(lds + (bufo) + bRow + (nh)*2048 + n2*1024 + 16384); \
    } } while (0)
#define MMQ(mlo, bfx, nlo) do { _Pragma("unroll")                          \
    for (int j = 0; j < 4; ++j) {                                          \
        acc[(mlo)+j][(nlo)  ] = MFMA_(afq[j][0], bfx[0][0], acc[(mlo)+j][(nlo)  ]); \
        acc[(mlo)+j][(nlo)  ] = MFMA_(afq[j][1], bfx[0][1], acc[(mlo)+j][(nlo)  ]); \
        acc[(mlo)+j][(nlo)+1] = MFMA_(afq[j][0], bfx[1][0], acc[(mlo)+j][(nlo)+1]); \
        acc[(mlo)+j][(nlo)+1] = MFMA_(afq[j][1], bfx[1][1], acc[(mlo)+j][(nlo)+1]); \
    } } while (0)

template<bool OUT_F32>
__global__ __launch_bounds__(512, 2)
void gemm256(const bf16_t* __restrict__ A, const bf16_t* __restrict__ B,
             void* __restrict__ Cv, int M, int N, int K, int nbn)
{
    __shared__ __align__(16) char lds[131072];

    const int nwg = gridDim.x;
    const int bid0 = blockIdx.x;
    const int bid = (bid0 & 7) * (nwg >> 3) + (bid0 >> 3);   // XCD swizzle
    const int bm = bid / nbn, bn = bid % nbn;
    const int t = threadIdx.x;
    const int lane = t & 63, wid = t >> 6;
    const int wm = wid >> 2, wn = wid & 3;          // 2M x 4N waves
    const int l15 = lane & 15, lg = lane >> 4;
    const int m0 = bm * 256, n0 = bn * 256;

    const int Krb = K * 2;
    const int srow = t >> 2;
    const int schunk = (((t & 3) ^ ((t >> 3) & 3)) << 4);    // pre-swizzled src
    const char* aS0 = (const char*)A + (size_t)(m0 + srow) * Krb + schunk;
    const char* aS1 = (const char*)A + (size_t)(m0 + 128 + srow) * Krb + schunk;
    const char* bS0 = (const char*)B + (size_t)(n0 + srow) * Krb + schunk;
    const char* bS1 = (const char*)B + (size_t)(n0 + 128 + srow) * Krb + schunk;
    char* sd = lds + t * 16;                                 // linear LDS dest

    const int rchunk = ((lg ^ ((l15 >> 1) & 3)) << 4);
    const int aRow = (wm * 128 + l15) * 64 + rchunk;
    const int bRow = 32768 + (wn * 64 + l15) * 64 + rchunk;

    const int NT = K >> 6;                                   // K-tiles of 64
    f32x4 acc[8][4] = {};
    bf16x8 afq[4][2], bf0[2][2], bf1[2][2];

    SA(0, 0, 0); SA(0, 1, 0); SB(0, 0, 0); SB(0, 1, 0);
    SB(65536, 0, 128); SB(65536, 1, 128);
    WVM4;
    BAR;

    for (int T = 0; T < NT; T += 2) {
        const int k1 = (T + 1) * 128;                        // K-byte offsets
        const int k2 = (T + 2 < NT) ? (T + 2) * 128 : 0;
        const int k3 = (T + 3 < NT) ? (T + 3) * 128 : 0;
        // P1: Q(0,0) of T (buf0)
        LDA(0, 0); LDB(0, 0, bf0); SA(65536, 0, k1); BAR; SCB;
        PRIO1; MMQ(0, bf0, 0); PRIO0; BAR;
        // P2: Q(0,1)
        LDB(0, 1, bf1); SA(65536, 1, k1); BAR; SCB;
        PRIO1; MMQ(0, bf1, 2); PRIO0; BAR;
        // P3: Q(1,1)
        LDA(0, 1); SB(0, 0, k2); BAR; SCB;
        PRIO1; MMQ(4, bf1, 2); PRIO0; BAR;
        // P4: Q(1,0)  (no reads)
        SB(0, 1, k2); BAR;
        PRIO1; MMQ(4, bf0, 0); PRIO0; WVM4; BAR;
        // P5: Q(0,0) of T+1 (buf1)
        LDA(65536, 0); LDB(65536, 0, bf0); SA(0, 0, k2); BAR; SCB;
        PRIO1; MMQ(0, bf0, 0); PRIO0; BAR;
        // P6: Q(0,1)
        LDB(65536, 1, bf1); SA(0, 1, k2); BAR; SCB;
        PRIO1; MMQ(0, bf1, 2); PRIO0; BAR;
        // P7: Q(1,1)
        LDA(65536, 1); SB(65536, 0, k3); BAR; SCB;
        PRIO1; MMQ(4, bf1, 2); PRIO0; BAR;
        // P8: Q(1,0)
        SB(65536, 1, k3); BAR;
        PRIO1; MMQ(4, bf0, 0); PRIO0; WVM4; BAR;
    }

    #pragma unroll
    for (int m = 0; m < 8; ++m) {
        int row0 = m0 + wm * 128 + m * 16 + lg * 4;
        #pragma unroll
        for (int n = 0; n < 4; ++n) {
            int col = n0 + wn * 64 + n * 16 + l15;
            #pragma unroll
            for (int i = 0; i < 4; ++i) {
                if constexpr (OUT_F32)
                    ((float*)Cv)[(size_t)(row0 + i) * N + col] = acc[m][n][i];
                else
                    ((bf16_t*)Cv)[(size_t)(row0 + i) * N + col] = (bf16_t)acc[m][n][i];
            }
        }
    }
}

// ---------------------------------------------------------------------------
// 128x128 m97-structure GEMM for the KV projection (unchanged).
// ---------------------------------------------------------------------------
template<int MODE>
__global__ __launch_bounds__(256, 4)
void gemm_bt(const bf16_t* __restrict__ A, const bf16_t* __restrict__ B,
             void* __restrict__ Cv, bf16_t* __restrict__ Vt,
             int M, int N, int K, int nbn)
{
    __shared__ __align__(16) bf16_t lA[128 * 32];
    __shared__ __align__(16) bf16_t lB[128 * 32];

    const int nwg = gridDim.x;
    const int bid0 = blockIdx.x;
    const int bid = (bid0 & 7) * (nwg >> 3) + (bid0 >> 3);
    const int bm = bid / nbn, bn = bid % nbn;
    const int t = threadIdx.x;
    const int lane = t & 63, wid = t >> 6;
    const int wrow = (wid >> 1) * 64, wcol = (wid & 1) * 64;
    const int l15 = lane & 15, lg = lane >> 4;
    const int m0 = bm * 128, n0 = bn * 128;

    const int r0 = t >> 2, pos0 = (t & 3) * 8;
    const int r1 = r0 + 64;

    const bf16_t* Ar0 = A + (size_t)(m0 + r0) * K + pos0;
    const bf16_t* Ar1 = A + (size_t)(m0 + r1) * K + pos0;
    const bf16_t* Br0 = B + (size_t)(n0 + r0) * K + pos0;
    const bf16_t* Br1 = B + (size_t)(n0 + r1) * K + pos0;

    f32x4 acc[4][4] = {};

    for (int k0 = 0; k0 < K; k0 += 32) {
        __syncthreads();
        GLOAD_LDS16(Ar0 + k0, lA + t * 8);
        GLOAD_LDS16(Ar1 + k0, lA + (t + 256) * 8);
        GLOAD_LDS16(Br0 + k0, lB + t * 8);
        GLOAD_LDS16(Br1 + k0, lB + (t + 256) * 8);
        __syncthreads();

        bf16x8 af[4], bfr[4];
        #pragma unroll
        for (int m = 0; m < 4; ++m)
            af[m] = *(const bf16x8*)(lA + (wrow + m * 16 + l15) * 32 + lg * 8);
        #pragma unroll
        for (int n = 0; n < 4; ++n)
            bfr[n] = *(const bf16x8*)(lB + (wcol + n * 16 + l15) * 32 + lg * 8);
        #pragma unroll
        for (int m = 0; m < 4; ++m)
            #pragma unroll
            for (int n = 0; n < 4; ++n)
                acc[m][n] = __builtin_amdgcn_mfma_f32_16x16x32_bf16(
                    af[m], bfr[n], acc[m][n], 0, 0, 0);
    }

    #pragma unroll
    for (int m = 0; m < 4; ++m) {
        #pragma unroll
        for (int n = 0; n < 4; ++n) {
            int col  = n0 + wcol + n * 16 + l15;
            int row0 = m0 + wrow + m * 16 + lg * 4;
            if constexpr (MODE == 0) {
                #pragma unroll
                for (int i = 0; i < 4; ++i)
                    ((bf16_t*)Cv)[(size_t)(row0 + i) * N + col] = (bf16_t)acc[m][n][i];
            } else if constexpr (MODE == 1) {
                #pragma unroll
                for (int i = 0; i < 4; ++i)
                    ((float*)Cv)[(size_t)(row0 + i) * N + col] = acc[m][n][i];
            } else {
                if (col < 1024) {
                    #pragma unroll
                    for (int i = 0; i < 4; ++i)
                        ((bf16_t*)Cv)[(size_t)(row0 + i) * 1024 + col] = (bf16_t)acc[m][n][i];
                } else {
                    bf16x4 pk;
                    #pragma unroll
                    for (int i = 0; i < 4; ++i) pk[i] = (bf16_t)acc[m][n][i];
                    *(bf16x4*)(Vt + (size_t)(col - 1024) * 4096 + row0) = pk;
                }
            }
        }
    }
}

// ---------------------------------------------------------------------------
// RoPE (interleaved pairs), in-place on bf16, 8 elems (4 pairs) per thread.
// oscale folds attention's 1/sqrt(HD)*log2(e) into Q.
// ---------------------------------------------------------------------------
__global__ __launch_bounds__(256)
void rope_kernel(bf16_t* __restrict__ X, const float* __restrict__ fc,
                 const float* __restrict__ fs, int nheads, int rowstride,
                 float oscale)
{
    int idx = blockIdx.x * 256 + threadIdx.x;
    int j4 = idx & 15;
    int rest = idx >> 4;
    int h = rest % nheads;
    int tok = rest / nheads;
    int s = tok & (SEQ - 1);
    bf16_t* p = X + (size_t)tok * rowstride + h * HDIM + j4 * 8;
    bf16x8 v = *(const bf16x8*)p;
    float4 c  = *(const float4*)(fc + s * 64 + j4 * 4);
    float4 sn = *(const float4*)(fs + s * 64 + j4 * 4);
    c.x *= oscale; c.y *= oscale; c.z *= oscale; c.w *= oscale;
    sn.x *= oscale; sn.y *= oscale; sn.z *= oscale; sn.w *= oscale;
    bf16x8 o;
    o[0] = (bf16_t)((float)v[0] * c.x - (float)v[1] * sn.x);
    o[1] = (bf16_t)((float)v[0] * sn.x + (float)v[1] * c.x);
    o[2] = (bf16_t)((float)v[2] * c.y - (float)v[3] * sn.y);
    o[3] = (bf16_t)((float)v[2] * sn.y + (float)v[3] * c.y);
    o[4] = (bf16_t)((float)v[4] * c.z - (float)v[5] * sn.z);
    o[5] = (bf16_t)((float)v[4] * sn.z + (float)v[5] * c.z);
    o[6] = (bf16_t)((float)v[6] * c.w - (float)v[7] * sn.w);
    o[7] = (bf16_t)((float)v[6] * sn.w + (float)v[7] * c.w);
    *(bf16x8*)p = o;
}

// ---------------------------------------------------------------------------
// Flash attention (round-11 version, best measured): fixed-shift softmax
// (exp2(s'-20), per-lane l), PV on 16x16x32 MFMA via permuted K-row map +
// cvt_pk + shfl_xor(16) A-frag assembly, double-buffered KV, QBLK=128.
// ---------------------------------------------------------------------------
__global__ __launch_bounds__(512, 2)
void attn_kernel(const bf16_t* __restrict__ Q, const bf16_t* __restrict__ Kg,
                 const bf16_t* __restrict__ Vtg, bf16_t* __restrict__ O)
{
    __shared__ __align__(16) char klds[2][64 * 256];    // K tiles, swizzled+row-permuted
    __shared__ __align__(16) char vlds[2][128 * 128];   // V^T tiles, swizzled

    const int nwg = gridDim.x;
    const int bid0 = blockIdx.x;
    const int blk = (bid0 & 7) * (nwg >> 3) + (bid0 >> 3);   // XCD swizzle
    const int qt = blk & 7;            // q-tile of 128 rows
    const int bh = blk >> 3;           // 0..127
    const int b = bh >> 5, h = bh & 31, kv = h >> 2;
    const int t = threadIdx.x, lane = t & 63, wid = t >> 6;  // wid 0..7
    const int l15 = lane & 15, lg = lane >> 4;
    const int swzk = (l15 & 7) << 4;

    const int qrow = qt * 128 + wid * 16 + l15;
    const size_t qbase = (size_t)(b * SEQ + qrow) * DMODEL + h * HDIM;
    bf16x8 qf[4];
    #pragma unroll
    for (int dc = 0; dc < 4; ++dc)
        qf[dc] = *(const bf16x8*)(Q + qbase + dc * 32 + lg * 8);

    const char* kgb = (const char*)Kg + ((size_t)(b * SEQ) * 1024 + kv * HDIM) * 2;
    const char* vgb = (const char*)Vtg + ((size_t)(kv * HDIM) * 4096 + b * SEQ) * 2;

    const int ck0 = t, ck1 = t + 512;
    const int kr0 = ck0 >> 4, kr1 = ck1 >> 4;
    const int kg0 = ((kr0 >> 5) << 5) + (((((kr0 & 15) >> 2) ^ ((kr0 >> 4) & 1)) << 3))
                  + (((kr0 >> 4) & 1) << 2) + (kr0 & 3);
    const int kg1 = ((kr1 >> 5) << 5) + (((((kr1 & 15) >> 2) ^ ((kr1 >> 4) & 1)) << 3))
                  + (((kr1 >> 4) & 1) << 2) + (kr1 & 3);
    const int kf0 = kg0 * 2048 + ((((ck0 & 15) << 4)) ^ ((kr0 & 7) << 4));
    const int kf1 = kg1 * 2048 + ((((ck1 & 15) << 4)) ^ ((kr1 & 7) << 4));
    const int vd0 = ck0 >> 3, vf0 = vd0 * 8192 + ((((ck0 & 7) << 4)) ^ ((vd0 & 7) << 4));
    const int vd1 = ck1 >> 3, vf1 = vd1 * 8192 + ((((ck1 & 7) << 4)) ^ ((vd1 & 7) << 4));

    f32x4 o[8] = {};
    float lrun = 0.f;

#define STAGE_KV(kt_, bi_) do {                                            \
    GLOAD_LDS16(kgb + (size_t)(kt_) * 131072 + kf0, klds[bi_] + ck0 * 16); \
    GLOAD_LDS16(kgb + (size_t)(kt_) * 131072 + kf1, klds[bi_] + ck1 * 16); \
    GLOAD_LDS16(vgb + (kt_) * 128 + vf0, vlds[bi_] + ck0 * 16);            \
    GLOAD_LDS16(vgb + (kt_) * 128 + vf1, vlds[bi_] + ck1 * 16);            \
} while (0)

    STAGE_KV(0, 0);
    __syncthreads();

    for (int kt = 0; kt < 16; ++kt) {
        const int cur = kt & 1;
        const int knx = (kt + 1 < 16) ? kt + 1 : 15;
        STAGE_KV(knx, cur ^ 1);                  // prefetch under compute

        f32x4 sacc[4] = {};
        #pragma unroll
        for (int kb = 0; kb < 4; ++kb) {
            const char* krow = klds[cur] + (kb * 16 + l15) * 256;
            #pragma unroll
            for (int dc = 0; dc < 4; ++dc) {
                bf16x8 kf = *(const bf16x8*)(krow + ((dc * 64 + lg * 16) ^ swzk));
                sacc[kb] = __builtin_amdgcn_mfma_f32_16x16x32_bf16(
                    kf, qf[dc], sacc[kb], 0, 0, 0);
            }
        }

        float ts = 0.f;
        unsigned qpk[4][2];
        #pragma unroll
        for (int kb = 0; kb < 4; ++kb) {
            float p0 = exp2f(sacc[kb][0] - 20.0f);
            float p1 = exp2f(sacc[kb][1] - 20.0f);
            float p2 = exp2f(sacc[kb][2] - 20.0f);
            float p3 = exp2f(sacc[kb][3] - 20.0f);
            ts += (p0 + p1) + (p2 + p3);
            asm("v_cvt_pk_bf16_f32 %0, %1, %2" : "=v"(qpk[kb][0]) : "v"(p0), "v"(p1));
            asm("v_cvt_pk_bf16_f32 %0, %1, %2" : "=v"(qpk[kb][1]) : "v"(p2), "v"(p3));
        }
        lrun += ts;

        #pragma unroll
        for (int c = 0; c < 2; ++c) {
            unsigned s0 = (unsigned)__shfl_xor((int)qpk[2 * c + 1][0], 16);
            unsigned s1 = (unsigned)__shfl_xor((int)qpk[2 * c + 1][1], 16);
            u32x4 w;
            w[0] = qpk[2 * c][0]; w[1] = qpk[2 * c][1]; w[2] = s0; w[3] = s1;
            bf16x8 a32 = __builtin_bit_cast(bf16x8, w);
            #pragma unroll
            for (int db = 0; db < 8; ++db) {
                int d = l15 + 16 * db;
                const char* va = vlds[cur] + d * 128 + ((c * 64 + lg * 16) ^ swzk);
                bf16x8 vf = *(const bf16x8*)va;
                o[db] = __builtin_amdgcn_mfma_f32_16x16x32_bf16(
                    a32, vf, o[db], 0, 0, 0);
            }
        }

        __syncthreads();
    }
#undef STAGE_KV

    lrun += __shfl_xor(lrun, 16);
    lrun += __shfl_xor(lrun, 32);

    #pragma unroll
    for (int i = 0; i < 4; ++i) {
        float li = __shfl(lrun, lg * 4 + i);
        float inv = 1.0f / li;
        int row = b * SEQ + qt * 128 + wid * 16 + lg * 4 + i;
        #pragma unroll
        for (int db = 0; db < 8; ++db) {
            int col = h * HDIM + l15 + 16 * db;
            O[(size_t)row * DMODEL + col] = (bf16_t)(o[db][i] * inv);
        }
    }
}

// ---------------------------------------------------------------------------
// Launch. Workspace (bf16): Qw 32M | Kw2 8M | Vt 8M | AO 32M | xb 32M |
// wqb 32M | wkvb 16M | wob 32M = 192 MiB.
// A/B this round: Q-proj on NEW gemm_mn (256x128, 2 blocks/CU);
// O-proj on OLD gemm256 (control).
// ---------------------------------------------------------------------------
extern "C" void kernel_launch(void* const* d_in, const int* in_sizes, int n_in,
                              void* d_out, int out_size, void* d_ws, size_t ws_size,
                              hipStream_t stream)
{
    const float* x  = (const float*)d_in[0];
    const float* wq = (const float*)d_in[1];
    const float* wk = (const float*)d_in[2];
    const float* wv = (const float*)d_in[3];
    const float* wo = (const float*)d_in[4];
    const float* fc = (const float*)d_in[5];
    const float* fs = (const float*)d_in[6];

    const size_t T = (size_t)4096;
    bf16_t* Qw   = (bf16_t*)d_ws;            // [4096][4096]
    bf16_t* Kw2  = Qw   + T * 4096;          // [4096][1024]
    bf16_t* Vt   = Kw2  + T * 1024;          // [1024(kv*128+d)][4096 tok]
    bf16_t* AO   = Vt   + T * 1024;          // [4096][4096]
    bf16_t* xb   = AO   + T * 4096;          // [4096][4096]
    bf16_t* wqb  = xb   + T * 4096;          // [4096][4096]
    bf16_t* wkvb = wqb  + T * 4096;          // [2048][4096]  (wk ; wv)
    bf16_t* wob  = wkvb + T * 2048;          // [4096][4096]

    f2b<<<8192, 256, 0, stream>>>(x,  xb,  4096 * 4096 / 8);
    f2b<<<8192, 256, 0, stream>>>(wq, wqb, 4096 * 4096 / 8);
    f2b<<<2048, 256, 0, stream>>>(wk, wkvb,                       1024 * 4096 / 8);
    f2b<<<2048, 256, 0, stream>>>(wv, wkvb + (size_t)1024 * 4096, 1024 * 4096 / 8);
    f2b<<<8192, 256, 0, stream>>>(wo, wob, 4096 * 4096 / 8);

    gemm_mn<false><<<512, 512, 0, stream>>>(xb, wqb, Qw, 4096, 4096, 4096, 32);
    gemm_bt<2><<<512, 256, 0, stream>>>(xb, wkvb, Kw2, Vt, 4096, 2048, 4096, 16);

    // Q prescale = (1/sqrt(128)) * log2(e): softmax becomes pure exp2
    rope_kernel<<<8192, 256, 0, stream>>>(Qw,  fc, fs, NHQ,  4096,
                                          0.08838834764831845f * 1.4426950408889634f);
    rope_kernel<<<2048, 256, 0, stream>>>(Kw2, fc, fs, NHKV, 1024, 1.0f);

    attn_kernel<<<1024, 512, 0, stream>>>(Qw, Kw2, Vt, AO);

    gemm256<true><<<256, 512, 0, stream>>>(AO, wob, d_out, 4096, 4096, 4096, 16);
}

// Round 17
// 470.040 us; speedup vs baseline: 1.1208x; 1.1208x over previous
//
#include <hip/hip_runtime.h>

typedef __bf16 bf16_t;
typedef __bf16 bf16x8 __attribute__((ext_vector_type(8)));
typedef __bf16 bf16x4 __attribute__((ext_vector_type(4)));
typedef float  f32x4  __attribute__((ext_vector_type(4)));
typedef unsigned u32x4 __attribute__((ext_vector_type(4)));

#define SEQ    1024
#define DMODEL 4096
#define NHQ    32
#define NHKV   8
#define HDIM   128

// async global->LDS, 16B per lane; LDS dest must be linear (base + lane*16)
#define GLOAD_LDS16(g, l)                                                  \
    __builtin_amdgcn_global_load_lds(                                      \
        (const __attribute__((address_space(1))) unsigned int*)(g),        \
        (__attribute__((address_space(3))) unsigned int*)(l), 16, 0, 0)

// ---------------------------------------------------------------------------
// fp32 -> bf16 convert, ALL five arrays in one launch (removes 4 launch
// gaps/tails). Segments by block range; 32 elems/thread.
//  blocks [0,2048)    : x    -> xb    (16.78M elems)
//  blocks [2048,4096) : wq   -> wqb
//  blocks [4096,4608) : wk   -> wkvb[0..4.19M)
//  blocks [4608,5120) : wv   -> wkvb[4.19M..)
//  blocks [5120,7168) : wo   -> wob
// ---------------------------------------------------------------------------
__global__ __launch_bounds__(256)
void f2b_all(const float* __restrict__ x,  const float* __restrict__ wq,
             const float* __restrict__ wk, const float* __restrict__ wv,
             const float* __restrict__ wo,
             bf16_t* __restrict__ xb,  bf16_t* __restrict__ wqb,
             bf16_t* __restrict__ wkvb, bf16_t* __restrict__ wob)
{
    const int bid = blockIdx.x;
    const float* src;
    bf16_t* dst;
    size_t base;
    if (bid < 2048)      { src = x;  dst = xb;   base = (size_t)bid * 8192; }
    else if (bid < 4096) { src = wq; dst = wqb;  base = (size_t)(bid - 2048) * 8192; }
    else if (bid < 4608) { src = wk; dst = wkvb; base = (size_t)(bid - 4096) * 8192; }
    else if (bid < 5120) { src = wv; dst = wkvb + (size_t)1024 * 4096;
                           base = (size_t)(bid - 4608) * 8192; }
    else                 { src = wo; dst = wob;  base = (size_t)(bid - 5120) * 8192; }

    size_t i0 = base + (size_t)threadIdx.x * 8;
    #pragma unroll
    for (int c = 0; c < 4; ++c) {
        size_t i = i0 + (size_t)c * 2048;
        const float4* p = (const float4*)(src + i);
        float4 a = p[0], b = p[1];
        bf16x8 o;
        o[0] = (bf16_t)a.x; o[1] = (bf16_t)a.y; o[2] = (bf16_t)a.z; o[3] = (bf16_t)a.w;
        o[4] = (bf16_t)b.x; o[5] = (bf16_t)b.y; o[6] = (bf16_t)b.z; o[7] = (bf16_t)b.w;
        *(bf16x8*)(dst + i) = o;
    }
}

#define MFMA_(a, b, c) __builtin_amdgcn_mfma_f32_16x16x32_bf16(a, b, c, 0, 0, 0)
#define BAR    __builtin_amdgcn_s_barrier()
#define SCB    __builtin_amdgcn_sched_barrier(0)
#define PRIO1  __builtin_amdgcn_s_setprio(1)
#define PRIO0  __builtin_amdgcn_s_setprio(0)
#define WVM4   do { asm volatile("s_waitcnt vmcnt(4)" ::: "memory"); SCB; } while (0)

// ---------------------------------------------------------------------------
// 256x256 8-wave GEMM -- ROUND-11 VERSION (best measured: 119 us, MfmaUtil
// 50%, 0 conflicts; plateau confirmed across 4 falsified alternatives).
// 8-phase, BK=64, dbuf over even/odd K-tiles, compiler-scheduled ds_reads,
// raw s_barriers, setprio, counted vmcnt(4) at P4/P8 BEFORE closing barrier.
// ---------------------------------------------------------------------------
#define SA(bufo, half, ktb)  do {                                          \
    const char* g_ = ((half) ? aS1 : aS0) + (ktb);                         \
    GLOAD_LDS16(g_,      sd + (bufo) + (half) * 8192);                     \
    GLOAD_LDS16(g_ + 64, sd + (bufo) + (half) * 8192 + 16384);             \
} while (0)
#define SB(bufo, half, ktb)  do {                                          \
    const char* g_ = ((half) ? bS1 : bS0) + (ktb);                         \
    GLOAD_LDS16(g_,      sd + (bufo) + 32768 + (half) * 8192);             \
    GLOAD_LDS16(g_ + 64, sd + (bufo) + 32768 + (half) * 8192 + 16384);     \
} while (0)
#define LDA(bufo, mh) do { _Pragma("unroll")                               \
    for (int j = 0; j < 4; ++j) {                                          \
        afq[j][0] = *(const bf16x8*)(lds + (bufo) + aRow + (mh)*4096 + j*1024);         \
        afq[j][1] = *(const bf16x8*)(lds + (bufo) + aRow + (mh)*4096 + j*1024 + 16384); \
    } } while (0)
#define LDB(bufo, nh, dst) do { _Pragma("unroll")                          \
    for (int n2 = 0; n2 < 2; ++n2) {                                       \
        dst[n2][0] = *(const bf16x8*)(lds + (bufo) + bRow + (nh)*2048 + n2*1024);         \
        dst[n2][1] = *(const bf16x8*)(lds + (bufo) + bRow + (nh)*2048 + n2*1024 + 16384); \
    } } while (0)
#define MMQ(mlo, bfx, nlo) do { _Pragma("unroll")                          \
    for (int j = 0; j < 4; ++j) {                                          \
        acc[(mlo)+j][(nlo)  ] = MFMA_(afq[j][0], bfx[0][0], acc[(mlo)+j][(nlo)  ]); \
        acc[(mlo)+j][(nlo)  ] = MFMA_(afq[j][1], bfx[0][1], acc[(mlo)+j][(nlo)  ]); \
        acc[(mlo)+j][(nlo)+1] = MFMA_(afq[j][0], bfx[1][0], acc[(mlo)+j][(nlo)+1]); \
        acc[(mlo)+j][(nlo)+1] = MFMA_(afq[j][1], bfx[1][1], acc[(mlo)+j][(nlo)+1]); \
    } } while (0)

template<bool OUT_F32>
__global__ __launch_bounds__(512, 2)
void gemm256(const bf16_t* __restrict__ A, const bf16_t* __restrict__ B,
             void* __restrict__ Cv, int M, int N, int K, int nbn)
{
    __shared__ __align__(16) char lds[131072];

    const int nwg = gridDim.x;
    const int bid0 = blockIdx.x;
    const int bid = (bid0 & 7) * (nwg >> 3) + (bid0 >> 3);   // XCD swizzle
    const int bm = bid / nbn, bn = bid % nbn;
    const int t = threadIdx.x;
    const int lane = t & 63, wid = t >> 6;
    const int wm = wid >> 2, wn = wid & 3;          // 2M x 4N waves
    const int l15 = lane & 15, lg = lane >> 4;
    const int m0 = bm * 256, n0 = bn * 256;

    const int Krb = K * 2;
    const int srow = t >> 2;
    const int schunk = (((t & 3) ^ ((t >> 3) & 3)) << 4);    // pre-swizzled src
    const char* aS0 = (const char*)A + (size_t)(m0 + srow) * Krb + schunk;
    const char* aS1 = (const char*)A + (size_t)(m0 + 128 + srow) * Krb + schunk;
    const char* bS0 = (const char*)B + (size_t)(n0 + srow) * Krb + schunk;
    const char* bS1 = (const char*)B + (size_t)(n0 + 128 + srow) * Krb + schunk;
    char* sd = lds + t * 16;                                 // linear LDS dest

    const int rchunk = ((lg ^ ((l15 >> 1) & 3)) << 4);
    const int aRow = (wm * 128 + l15) * 64 + rchunk;
    const int bRow = 32768 + (wn * 64 + l15) * 64 + rchunk;

    const int NT = K >> 6;                                   // K-tiles of 64
    f32x4 acc[8][4] = {};
    bf16x8 afq[4][2], bf0[2][2], bf1[2][2];

    SA(0, 0, 0); SA(0, 1, 0); SB(0, 0, 0); SB(0, 1, 0);
    SB(65536, 0, 128); SB(65536, 1, 128);
    WVM4;
    BAR;

    for (int T = 0; T < NT; T += 2) {
        const int k1 = (T + 1) * 128;                        // K-byte offsets
        const int k2 = (T + 2 < NT) ? (T + 2) * 128 : 0;
        const int k3 = (T + 3 < NT) ? (T + 3) * 128 : 0;
        // P1: Q(0,0) of T (buf0)
        LDA(0, 0); LDB(0, 0, bf0); SA(65536, 0, k1); BAR; SCB;
        PRIO1; MMQ(0, bf0, 0); PRIO0; BAR;
        // P2: Q(0,1)
        LDB(0, 1, bf1); SA(65536, 1, k1); BAR; SCB;
        PRIO1; MMQ(0, bf1, 2); PRIO0; BAR;
        // P3: Q(1,1)
        LDA(0, 1); SB(0, 0, k2); BAR; SCB;
        PRIO1; MMQ(4, bf1, 2); PRIO0; BAR;
        // P4: Q(1,0)  (no reads)
        SB(0, 1, k2); BAR;
        PRIO1; MMQ(4, bf0, 0); PRIO0; WVM4; BAR;
        // P5: Q(0,0) of T+1 (buf1)
        LDA(65536, 0); LDB(65536, 0, bf0); SA(0, 0, k2); BAR; SCB;
        PRIO1; MMQ(0, bf0, 0); PRIO0; BAR;
        // P6: Q(0,1)
        LDB(65536, 1, bf1); SA(0, 1, k2); BAR; SCB;
        PRIO1; MMQ(0, bf1, 2); PRIO0; BAR;
        // P7: Q(1,1)
        LDA(65536, 1); SB(65536, 0, k3); BAR; SCB;
        PRIO1; MMQ(4, bf1, 2); PRIO0; BAR;
        // P8: Q(1,0)
        SB(65536, 1, k3); BAR;
        PRIO1; MMQ(4, bf0, 0); PRIO0; WVM4; BAR;
    }

    #pragma unroll
    for (int m = 0; m < 8; ++m) {
        int row0 = m0 + wm * 128 + m * 16 + lg * 4;
        #pragma unroll
        for (int n = 0; n < 4; ++n) {
            int col = n0 + wn * 64 + n * 16 + l15;
            #pragma unroll
            for (int i = 0; i < 4; ++i) {
                if constexpr (OUT_F32)
                    ((float*)Cv)[(size_t)(row0 + i) * N + col] = acc[m][n][i];
                else
                    ((bf16_t*)Cv)[(size_t)(row0 + i) * N + col] = (bf16_t)acc[m][n][i];
            }
        }
    }
}

// ---------------------------------------------------------------------------
// 128x128 m97-structure GEMM for the KV projection (unchanged).
// MODE 2 epilogue: cols <1024 -> K buffer; cols >=1024 transposed to
// Vt[(col-1024)][tok] as contiguous bf16x4 stores.
// ---------------------------------------------------------------------------
template<int MODE>
__global__ __launch_bounds__(256, 4)
void gemm_bt(const bf16_t* __restrict__ A, const bf16_t* __restrict__ B,
             void* __restrict__ Cv, bf16_t* __restrict__ Vt,
             int M, int N, int K, int nbn)
{
    __shared__ __align__(16) bf16_t lA[128 * 32];
    __shared__ __align__(16) bf16_t lB[128 * 32];

    const int nwg = gridDim.x;
    const int bid0 = blockIdx.x;
    const int bid = (bid0 & 7) * (nwg >> 3) + (bid0 >> 3);
    const int bm = bid / nbn, bn = bid % nbn;
    const int t = threadIdx.x;
    const int lane = t & 63, wid = t >> 6;
    const int wrow = (wid >> 1) * 64, wcol = (wid & 1) * 64;
    const int l15 = lane & 15, lg = lane >> 4;
    const int m0 = bm * 128, n0 = bn * 128;

    const int r0 = t >> 2, pos0 = (t & 3) * 8;
    const int r1 = r0 + 64;

    const bf16_t* Ar0 = A + (size_t)(m0 + r0) * K + pos0;
    const bf16_t* Ar1 = A + (size_t)(m0 + r1) * K + pos0;
    const bf16_t* Br0 = B + (size_t)(n0 + r0) * K + pos0;
    const bf16_t* Br1 = B + (size_t)(n0 + r1) * K + pos0;

    f32x4 acc[4][4] = {};

    for (int k0 = 0; k0 < K; k0 += 32) {
        __syncthreads();
        GLOAD_LDS16(Ar0 + k0, lA + t * 8);
        GLOAD_LDS16(Ar1 + k0, lA + (t + 256) * 8);
        GLOAD_LDS16(Br0 + k0, lB + t * 8);
        GLOAD_LDS16(Br1 + k0, lB + (t + 256) * 8);
        __syncthreads();

        bf16x8 af[4], bfr[4];
        #pragma unroll
        for (int m = 0; m < 4; ++m)
            af[m] = *(const bf16x8*)(lA + (wrow + m * 16 + l15) * 32 + lg * 8);
        #pragma unroll
        for (int n = 0; n < 4; ++n)
            bfr[n] = *(const bf16x8*)(lB + (wcol + n * 16 + l15) * 32 + lg * 8);
        #pragma unroll
        for (int m = 0; m < 4; ++m)
            #pragma unroll
            for (int n = 0; n < 4; ++n)
                acc[m][n] = __builtin_amdgcn_mfma_f32_16x16x32_bf16(
                    af[m], bfr[n], acc[m][n], 0, 0, 0);
    }

    #pragma unroll
    for (int m = 0; m < 4; ++m) {
        #pragma unroll
        for (int n = 0; n < 4; ++n) {
            int col  = n0 + wcol + n * 16 + l15;
            int row0 = m0 + wrow + m * 16 + lg * 4;
            if constexpr (MODE == 0) {
                #pragma unroll
                for (int i = 0; i < 4; ++i)
                    ((bf16_t*)Cv)[(size_t)(row0 + i) * N + col] = (bf16_t)acc[m][n][i];
            } else if constexpr (MODE == 1) {
                #pragma unroll
                for (int i = 0; i < 4; ++i)
                    ((float*)Cv)[(size_t)(row0 + i) * N + col] = acc[m][n][i];
            } else {
                if (col < 1024) {
                    #pragma unroll
                    for (int i = 0; i < 4; ++i)
                        ((bf16_t*)Cv)[(size_t)(row0 + i) * 1024 + col] = (bf16_t)acc[m][n][i];
                } else {
                    bf16x4 pk;
                    #pragma unroll
                    for (int i = 0; i < 4; ++i) pk[i] = (bf16_t)acc[m][n][i];
                    *(bf16x4*)(Vt + (size_t)(col - 1024) * 4096 + row0) = pk;
                }
            }
        }
    }
}

// ---------------------------------------------------------------------------
// RoPE for Q and K in ONE launch (removes a launch gap). Blocks [0,8192):
// Q (nheads=32, stride 4096, oscale=log2(e)/sqrt(128)); blocks [8192,10240):
// K (nheads=8, stride 1024, oscale=1). Math identical to the r11 kernel.
// ---------------------------------------------------------------------------
__global__ __launch_bounds__(256)
void rope2(bf16_t* __restrict__ Qx, bf16_t* __restrict__ Kx,
           const float* __restrict__ fc, const float* __restrict__ fs,
           float qscale)
{
    const int bid = blockIdx.x;
    bf16_t* X;
    int nheads, rowstride, idx;
    float oscale;
    if (bid < 8192) { X = Qx; nheads = NHQ;  rowstride = 4096; oscale = qscale;
                      idx = bid * 256 + threadIdx.x; }
    else            { X = Kx; nheads = NHKV; rowstride = 1024; oscale = 1.0f;
                      idx = (bid - 8192) * 256 + threadIdx.x; }
    int j4 = idx & 15;
    int rest = idx >> 4;
    int h = rest % nheads;
    int tok = rest / nheads;
    int s = tok & (SEQ - 1);
    bf16_t* p = X + (size_t)tok * rowstride + h * HDIM + j4 * 8;
    bf16x8 v = *(const bf16x8*)p;
    float4 c  = *(const float4*)(fc + s * 64 + j4 * 4);
    float4 sn = *(const float4*)(fs + s * 64 + j4 * 4);
    c.x *= oscale; c.y *= oscale; c.z *= oscale; c.w *= oscale;
    sn.x *= oscale; sn.y *= oscale; sn.z *= oscale; sn.w *= oscale;
    bf16x8 o;
    o[0] = (bf16_t)((float)v[0] * c.x - (float)v[1] * sn.x);
    o[1] = (bf16_t)((float)v[0] * sn.x + (float)v[1] * c.x);
    o[2] = (bf16_t)((float)v[2] * c.y - (float)v[3] * sn.y);
    o[3] = (bf16_t)((float)v[2] * sn.y + (float)v[3] * c.y);
    o[4] = (bf16_t)((float)v[4] * c.z - (float)v[5] * sn.z);
    o[5] = (bf16_t)((float)v[4] * sn.z + (float)v[5] * c.z);
    o[6] = (bf16_t)((float)v[6] * c.w - (float)v[7] * sn.w);
    o[7] = (bf16_t)((float)v[6] * sn.w + (float)v[7] * c.w);
    *(bf16x8*)p = o;
}

// ---------------------------------------------------------------------------
// Flash attention (round-11 version, best measured): fixed-shift softmax
// (exp2(s'-20), per-lane l), PV on 16x16x32 MFMA via permuted K-row map +
// cvt_pk + shfl_xor(16) A-frag assembly, double-buffered KV, QBLK=128.
// ---------------------------------------------------------------------------
__global__ __launch_bounds__(512, 2)
void attn_kernel(const bf16_t* __restrict__ Q, const bf16_t* __restrict__ Kg,
                 const bf16_t* __restrict__ Vtg, bf16_t* __restrict__ O)
{
    __shared__ __align__(16) char klds[2][64 * 256];    // K tiles, swizzled+row-permuted
    __shared__ __align__(16) char vlds[2][128 * 128];   // V^T tiles, swizzled

    const int nwg = gridDim.x;
    const int bid0 = blockIdx.x;
    const int blk = (bid0 & 7) * (nwg >> 3) + (bid0 >> 3);   // XCD swizzle
    const int qt = blk & 7;            // q-tile of 128 rows
    const int bh = blk >> 3;           // 0..127
    const int b = bh >> 5, h = bh & 31, kv = h >> 2;
    const int t = threadIdx.x, lane = t & 63, wid = t >> 6;  // wid 0..7
    const int l15 = lane & 15, lg = lane >> 4;
    const int swzk = (l15 & 7) << 4;

    const int qrow = qt * 128 + wid * 16 + l15;
    const size_t qbase = (size_t)(b * SEQ + qrow) * DMODEL + h * HDIM;
    bf16x8 qf[4];
    #pragma unroll
    for (int dc = 0; dc < 4; ++dc)
        qf[dc] = *(const bf16x8*)(Q + qbase + dc * 32 + lg * 8);

    const char* kgb = (const char*)Kg + ((size_t)(b * SEQ) * 1024 + kv * HDIM) * 2;
    const char* vgb = (const char*)Vtg + ((size_t)(kv * HDIM) * 4096 + b * SEQ) * 2;

    const int ck0 = t, ck1 = t + 512;
    const int kr0 = ck0 >> 4, kr1 = ck1 >> 4;
    const int kg0 = ((kr0 >> 5) << 5) + (((((kr0 & 15) >> 2) ^ ((kr0 >> 4) & 1)) << 3))
                  + (((kr0 >> 4) & 1) << 2) + (kr0 & 3);
    const int kg1 = ((kr1 >> 5) << 5) + (((((kr1 & 15) >> 2) ^ ((kr1 >> 4) & 1)) << 3))
                  + (((kr1 >> 4) & 1) << 2) + (kr1 & 3);
    const int kf0 = kg0 * 2048 + ((((ck0 & 15) << 4)) ^ ((kr0 & 7) << 4));
    const int kf1 = kg1 * 2048 + ((((ck1 & 15) << 4)) ^ ((kr1 & 7) << 4));
    const int vd0 = ck0 >> 3, vf0 = vd0 * 8192 + ((((ck0 & 7) << 4)) ^ ((vd0 & 7) << 4));
    const int vd1 = ck1 >> 3, vf1 = vd1 * 8192 + ((((ck1 & 7) << 4)) ^ ((vd1 & 7) << 4));

    f32x4 o[8] = {};
    float lrun = 0.f;

#define STAGE_KV(kt_, bi_) do {                                            \
    GLOAD_LDS16(kgb + (size_t)(kt_) * 131072 + kf0, klds[bi_] + ck0 * 16); \
    GLOAD_LDS16(kgb + (size_t)(kt_) * 131072 + kf1, klds[bi_] + ck1 * 16); \
    GLOAD_LDS16(vgb + (kt_) * 128 + vf0, vlds[bi_] + ck0 * 16);            \
    GLOAD_LDS16(vgb + (kt_) * 128 + vf1, vlds[bi_] + ck1 * 16);            \
} while (0)

    STAGE_KV(0, 0);
    __syncthreads();

    for (int kt = 0; kt < 16; ++kt) {
        const int cur = kt & 1;
        const int knx = (kt + 1 < 16) ? kt + 1 : 15;
        STAGE_KV(knx, cur ^ 1);                  // prefetch under compute

        f32x4 sacc[4] = {};
        #pragma unroll
        for (int kb = 0; kb < 4; ++kb) {
            const char* krow = klds[cur] + (kb * 16 + l15) * 256;
            #pragma unroll
            for (int dc = 0; dc < 4; ++dc) {
                bf16x8 kf = *(const bf16x8*)(krow + ((dc * 64 + lg * 16) ^ swzk));
                sacc[kb] = __builtin_amdgcn_mfma_f32_16x16x32_bf16(
                    kf, qf[dc], sacc[kb], 0, 0, 0);
            }
        }

        float ts = 0.f;
        unsigned qpk[4][2];
        #pragma unroll
        for (int kb = 0; kb < 4; ++kb) {
            float p0 = exp2f(sacc[kb][0] - 20.0f);
            float p1 = exp2f(sacc[kb][1] - 20.0f);
            float p2 = exp2f(sacc[kb][2] - 20.0f);
            float p3 = exp2f(sacc[kb][3] - 20.0f);
            ts += (p0 + p1) + (p2 + p3);
            asm("v_cvt_pk_bf16_f32 %0, %1, %2" : "=v"(qpk[kb][0]) : "v"(p0), "v"(p1));
            asm("v_cvt_pk_bf16_f32 %0, %1, %2" : "=v"(qpk[kb][1]) : "v"(p2), "v"(p3));
        }
        lrun += ts;

        #pragma unroll
        for (int c = 0; c < 2; ++c) {
            unsigned s0 = (unsigned)__shfl_xor((int)qpk[2 * c + 1][0], 16);
            unsigned s1 = (unsigned)__shfl_xor((int)qpk[2 * c + 1][1], 16);
            u32x4 w;
            w[0] = qpk[2 * c][0]; w[1] = qpk[2 * c][1]; w[2] = s0; w[3] = s1;
            bf16x8 a32 = __builtin_bit_cast(bf16x8, w);
            #pragma unroll
            for (int db = 0; db < 8; ++db) {
                int d = l15 + 16 * db;
                const char* va = vlds[cur] + d * 128 + ((c * 64 + lg * 16) ^ swzk);
                bf16x8 vf = *(const bf16x8*)va;
                o[db] = __builtin_amdgcn_mfma_f32_16x16x32_bf16(
                    a32, vf, o[db], 0, 0, 0);
            }
        }

        __syncthreads();
    }
#undef STAGE_KV

    lrun += __shfl_xor(lrun, 16);
    lrun += __shfl_xor(lrun, 32);

    #pragma unroll
    for (int i = 0; i < 4; ++i) {
        float li = __shfl(lrun, lg * 4 + i);
        float inv = 1.0f / li;
        int row = b * SEQ + qt * 128 + wid * 16 + lg * 4 + i;
        #pragma unroll
        for (int db = 0; db < 8; ++db) {
            int col = h * HDIM + l15 + 16 * db;
            O[(size_t)row * DMODEL + col] = (bf16_t)(o[db][i] * inv);
        }
    }
}

// ---------------------------------------------------------------------------
// Launch. Workspace (bf16): Qw 32M | Kw2 8M | Vt 8M | AO 32M | xb 32M |
// wqb 32M | wkvb 16M | wob 32M = 192 MiB.
// ---------------------------------------------------------------------------
extern "C" void kernel_launch(void* const* d_in, const int* in_sizes, int n_in,
                              void* d_out, int out_size, void* d_ws, size_t ws_size,
                              hipStream_t stream)
{
    const float* x  = (const float*)d_in[0];
    const float* wq = (const float*)d_in[1];
    const float* wk = (const float*)d_in[2];
    const float* wv = (const float*)d_in[3];
    const float* wo = (const float*)d_in[4];
    const float* fc = (const float*)d_in[5];
    const float* fs = (const float*)d_in[6];

    const size_t T = (size_t)4096;
    bf16_t* Qw   = (bf16_t*)d_ws;            // [4096][4096]
    bf16_t* Kw2  = Qw   + T * 4096;          // [4096][1024]
    bf16_t* Vt   = Kw2  + T * 1024;          // [1024(kv*128+d)][4096 tok]
    bf16_t* AO   = Vt   + T * 1024;          // [4096][4096]
    bf16_t* xb   = AO   + T * 4096;          // [4096][4096]
    bf16_t* wqb  = xb   + T * 4096;          // [4096][4096]
    bf16_t* wkvb = wqb  + T * 4096;          // [2048][4096]  (wk ; wv)
    bf16_t* wob  = wkvb + T * 2048;          // [4096][4096]

    f2b_all<<<7168, 256, 0, stream>>>(x, wq, wk, wv, wo, xb, wqb, wkvb, wob);

    gemm256<false><<<256, 512, 0, stream>>>(xb, wqb, Qw, 4096, 4096, 4096, 16);
    gemm_bt<2><<<512, 256, 0, stream>>>(xb, wkvb, Kw2, Vt, 4096, 2048, 4096, 16);

    // Q prescale = (1/sqrt(128)) * log2(e): softmax becomes pure exp2
    rope2<<<10240, 256, 0, stream>>>(Qw, Kw2, fc, fs,
                                     0.08838834764831845f * 1.4426950408889634f);

    attn_kernel<<<1024, 512, 0, stream>>>(Qw, Kw2, Vt, AO);

    gemm256<true><<<256, 512, 0, stream>>>(AO, wob, d_out, 4096, 4096, 4096, 16);
}